// Round 11
// baseline (85.921 us; speedup 1.0000x reference)
//
#include <hip/hip_runtime.h>
#include <hip/hip_bf16.h>

#define VOCAB 50257
#define HID 512
#define LABELS 64
#define TILEV 256          // vocab cols per block
#define CHUNK 16           // K rows per LDS chunk
#define APITCH 260         // 256 + 4 pad
#define BPITCH 68          // 64 + 4 pad

// ---------------------------------------------------------------------------
// K0: C[l] = b2[l] + sum_h b1[h] * w2[l][h]   (v-independent bias term)
// ---------------------------------------------------------------------------
__global__ void bias_combine(const float* __restrict__ b1,
                             const float* __restrict__ w2,
                             const float* __restrict__ b2,
                             float* __restrict__ C)
{
    int l = threadIdx.x;   // 64 threads
    float s = b2[l];
    for (int h = 0; h < HID; h += 4) {
        float4 wv = *(const float4*)&w2[l * HID + h];
        float4 bv = *(const float4*)&b1[h];
        s += wv.x * bv.x + wv.y * bv.y + wv.z * bv.z + wv.w * bv.w;
    }
    C[l] = s;
}

// ---------------------------------------------------------------------------
// K1: P[s][v][l] = sum_{h in split s} w1[h,v]*w2[l,h]
// 256 threads, tile 256 vocab x 64 labels, 8x8 acc per thread:
// per wave-hh 4 ds_read_b128 per 64 FMA (vs R10's 2 per 16) -> LDS-issue
// floor halves 63 -> 31.5us. Chunk=16 keeps prefetch regs at 16+4 per set.
// R10-proven alternating dual-register-set prefetch (T14) retained.
// Conflict-free LDS: A dual col groups {tx*4, 128+tx*4}; B b128 pair at
// ty*8 (8-lane broadcast); staging writes stride-1.
// ---------------------------------------------------------------------------
#define LOAD_CHUNK(areg, breg, h0)                                            \
    {                                                                         \
        if (full) {                                                           \
            _Pragma("unroll")                                                 \
            for (int i = 0; i < CHUNK; ++i)                                   \
                areg[i] = w1[(size_t)((h0) + i) * VOCAB + vv];                \
        } else {                                                              \
            _Pragma("unroll")                                                 \
            for (int i = 0; i < CHUNK; ++i)                                   \
                areg[i] = (vv < VOCAB)                                        \
                    ? w1[(size_t)((h0) + i) * VOCAB + vv] : 0.f;              \
        }                                                                     \
        breg = *(const float4*)&w2[lane * HID + (h0) + hq * 4];               \
    }

#define WRITE_CHUNK(areg, breg)                                               \
    {                                                                         \
        _Pragma("unroll")                                                     \
        for (int i = 0; i < CHUNK; ++i)                                       \
            lds_a[i * APITCH + t] = areg[i];                                  \
        {                                                                     \
            int hr = hq * 4;                                                  \
            lds_b[(hr + 0) * BPITCH + lane] = breg.x;                         \
            lds_b[(hr + 1) * BPITCH + lane] = breg.y;                         \
            lds_b[(hr + 2) * BPITCH + lane] = breg.z;                         \
            lds_b[(hr + 3) * BPITCH + lane] = breg.w;                         \
        }                                                                     \
    }

#define COMPUTE_CHUNK()                                                       \
    {                                                                         \
        _Pragma("unroll 4")                                                   \
        for (int hh = 0; hh < CHUNK; ++hh) {                                  \
            float4 a0 = *(const float4*)&lds_a[hh * APITCH + tx * 4];         \
            float4 a1 = *(const float4*)&lds_a[hh * APITCH + 128 + tx * 4];   \
            float4 b0 = *(const float4*)&lds_b[hh * BPITCH + ty * 8];         \
            float4 b1v = *(const float4*)&lds_b[hh * BPITCH + ty * 8 + 4];    \
            float av[8] = {a0.x, a0.y, a0.z, a0.w, a1.x, a1.y, a1.z, a1.w};   \
            float bv[8] = {b0.x, b0.y, b0.z, b0.w, b1v.x, b1v.y, b1v.z, b1v.w}; \
            _Pragma("unroll")                                                 \
            for (int i = 0; i < 8; ++i)                                       \
                _Pragma("unroll")                                             \
                for (int j = 0; j < 8; ++j)                                   \
                    acc[i][j] += av[i] * bv[j];                               \
        }                                                                     \
    }

__global__ __launch_bounds__(256) void build_partial(
    const float* __restrict__ w1,   // [HID][VOCAB]
    const float* __restrict__ w2,   // [LABELS][HID]
    float* __restrict__ P,          // [ksplit][VOCAB][LABELS]
    int klen)                       // 128; klen/CHUNK even
{
    __shared__ float lds_a[CHUNK * APITCH];  // [hh][col 0..255]
    __shared__ float lds_b[CHUNK * BPITCH];  // [hh][label 0..63]

    const int t     = threadIdx.x;      // 0..255
    const int lane  = t & 63;
    const int hq    = t >> 6;           // 0..3 (B-stage h-quad)
    const int v0    = blockIdx.x * TILEV;
    const int hbase = blockIdx.y * klen;
    float* Pout = P + (size_t)blockIdx.y * VOCAB * LABELS;
    const int tx = t & 31;              // col groups: tx*4 and 128+tx*4
    const int ty = t >> 5;              // labels ty*8 .. +7
    const bool full = (v0 + TILEV <= VOCAB);
    const int vv = v0 + t;              // staging column for this thread

    float acc[8][8] = {};

    float  a0[CHUNK], a1[CHUNK];
    float4 p0, p1;

    const int nch = klen / CHUNK;       // 8 (even)

    LOAD_CHUNK(a0, p0, hbase);          // prologue: chunk 0 in flight

    for (int cp = 0; cp < nch; cp += 2) {
        WRITE_CHUNK(a0, p0);            // waits on set0 loads
        __syncthreads();
        if (cp + 1 < nch) LOAD_CHUNK(a1, p1, hbase + (cp + 1) * CHUNK);
        COMPUTE_CHUNK();                // overlaps set1 flight
        __syncthreads();

        WRITE_CHUNK(a1, p1);
        __syncthreads();
        if (cp + 2 < nch) LOAD_CHUNK(a0, p0, hbase + (cp + 2) * CHUNK);
        COMPUTE_CHUNK();
        __syncthreads();
    }

    // store: cols v0 + {tx*4+i, 128+tx*4+i}, labels ty*8..+7
#pragma unroll
    for (int i = 0; i < 8; ++i) {
        int col = (i < 4) ? (tx * 4 + i) : (128 + tx * 4 + (i - 4));
        int v = v0 + col;
        if (full || v < VOCAB) {
            *(float4*)&Pout[(size_t)v * LABELS + ty * 8] =
                make_float4(acc[i][0], acc[i][1], acc[i][2], acc[i][3]);
            *(float4*)&Pout[(size_t)v * LABELS + ty * 8 + 4] =
                make_float4(acc[i][4], acc[i][5], acc[i][6], acc[i][7]);
        }
    }
}

// ---------------------------------------------------------------------------
// K1 fallback (small ws): folded-b1 single-buffer version (R7, measured-good).
// ---------------------------------------------------------------------------
__global__ __launch_bounds__(256) void build_partial_folded(
    const float* __restrict__ w1,
    const float* __restrict__ b1,
    const float* __restrict__ w2,
    float* __restrict__ P,
    int klen)
{
    __shared__ float lds_a[32 * 68];
    __shared__ float lds_b[32 * 68];

    const int t     = threadIdx.x;
    const int v0    = blockIdx.x * 64;
    const int hbase = blockIdx.y * klen;
    float* Pout = P + (size_t)blockIdx.y * VOCAB * LABELS;
    const int tx = t & 15;
    const int ty = t >> 4;
    const bool full = (v0 + 64 <= VOCAB);

    float acc[4][4] = {};

    for (int h0 = hbase; h0 < hbase + klen; h0 += 32) {
#pragma unroll
        for (int i = 0; i < 8; ++i) {
            int e   = t + 256 * i;
            int row = e >> 6;
            int col = e & 63;
            int v   = v0 + col;
            float a = (full || v < VOCAB) ? w1[(size_t)(h0 + row) * VOCAB + v] : 0.f;
            lds_a[row * 68 + col] = a + b1[h0 + row];
        }
#pragma unroll
        for (int i = 0; i < 2; ++i) {
            int e   = t + 256 * i;
            int hh4 = e >> 6;
            int l   = e & 63;
            float4 bv = *(const float4*)&w2[l * HID + h0 + hh4 * 4];
            lds_b[(hh4 * 4 + 0) * 68 + l] = bv.x;
            lds_b[(hh4 * 4 + 1) * 68 + l] = bv.y;
            lds_b[(hh4 * 4 + 2) * 68 + l] = bv.z;
            lds_b[(hh4 * 4 + 3) * 68 + l] = bv.w;
        }
        __syncthreads();
#pragma unroll
        for (int hh = 0; hh < 32; ++hh) {
            float4 a = *(const float4*)&lds_a[hh * 68 + tx * 4];
            float4 b = *(const float4*)&lds_b[hh * 68 + ty * 4];
            acc[0][0] += a.x * b.x; acc[0][1] += a.x * b.y; acc[0][2] += a.x * b.z; acc[0][3] += a.x * b.w;
            acc[1][0] += a.y * b.x; acc[1][1] += a.y * b.y; acc[1][2] += a.y * b.z; acc[1][3] += a.y * b.w;
            acc[2][0] += a.z * b.x; acc[2][1] += a.z * b.y; acc[2][2] += a.z * b.z; acc[2][3] += a.z * b.w;
            acc[3][0] += a.w * b.x; acc[3][1] += a.w * b.y; acc[3][2] += a.w * b.z; acc[3][3] += a.w * b.w;
        }
        __syncthreads();
    }

#pragma unroll
    for (int i = 0; i < 4; ++i) {
        int v = v0 + tx * 4 + i;
        if (v < VOCAB) {
            *(float4*)&Pout[(size_t)v * LABELS + ty * 4] =
                make_float4(acc[i][0], acc[i][1], acc[i][2], acc[i][3]);
        }
    }
}

// ---------------------------------------------------------------------------
// K2: out[tok][l] = sum_s P[s][idx[tok]][l] + bias[l]
// ---------------------------------------------------------------------------
__global__ __launch_bounds__(256) void gather_out(
    const int* __restrict__ idx,
    const float* __restrict__ P,
    const float* __restrict__ bias,
    float* __restrict__ out,
    int ntok, int ksplit)
{
    int g   = blockIdx.x * 256 + threadIdx.x;
    int tok = g >> 4;
    int j   = g & 15;
    if (tok >= ntok) return;
    int v = idx[tok];
    float4 s = ((const float4*)bias)[j];
    const float4* p = (const float4*)P + (size_t)v * 16 + j;
    for (int k = 0; k < ksplit; ++k) {
        float4 m = p[(size_t)k * VOCAB * 16];
        s.x += m.x; s.y += m.y; s.z += m.z; s.w += m.w;
    }
    ((float4*)out)[(size_t)tok * 16 + j] = s;
}

// ---------------------------------------------------------------------------
// Fallback (ws too small for any table): direct per-token dot.
// ---------------------------------------------------------------------------
__global__ __launch_bounds__(256) void direct_kernel(
    const int* __restrict__ idx,
    const float* __restrict__ w1,
    const float* __restrict__ b1,
    const float* __restrict__ w2,
    const float* __restrict__ b2,
    float* __restrict__ out,
    int ntok)
{
    int g   = blockIdx.x * 256 + threadIdx.x;
    int tok = g >> 6;
    int l   = g & 63;
    if (tok >= ntok) return;
    int v = idx[tok];
    float acc = b2[l];
    for (int h = 0; h < HID; ++h)
        acc += (w1[(size_t)h * VOCAB + v] + b1[h]) * w2[l * HID + h];
    out[(size_t)tok * 64 + l] = acc;
}

extern "C" void kernel_launch(void* const* d_in, const int* in_sizes, int n_in,
                              void* d_out, int out_size, void* d_ws, size_t ws_size,
                              hipStream_t stream) {
    const int*   idx = (const int*)d_in[0];
    const float* w1  = (const float*)d_in[1];
    const float* b1  = (const float*)d_in[2];
    const float* w2  = (const float*)d_in[3];
    const float* b2  = (const float*)d_in[4];
    float* out = (float*)d_out;
    const int ntok = in_sizes[0];   // 8*4096 = 32768

    const size_t table_bytes = (size_t)VOCAB * LABELS * sizeof(float);  // ~12.9 MB
    const int nblk2 = (ntok * 16 + 255) / 256;                          // 2048

    if (ws_size >= 4 * table_bytes + 1024) {
        // fast path: t=8 prefetch build (pure product) + combined bias in tail
        float* P = (float*)d_ws;
        float* C = (float*)((char*)d_ws + 4 * table_bytes);
        bias_combine<<<1, 64, 0, stream>>>(b1, w2, b2, C);
        dim3 grid1((VOCAB + TILEV - 1) / TILEV, 4);   // 197 x 4
        build_partial<<<grid1, 256, 0, stream>>>(w1, w2, P, HID / 4);
        gather_out<<<nblk2, 256, 0, stream>>>(idx, P, C, out, ntok, 4);
    } else {
        int ksplit = 0;
        if      (ws_size >= 4 * table_bytes) ksplit = 4;
        else if (ws_size >= 2 * table_bytes) ksplit = 2;
        else if (ws_size >= 1 * table_bytes) ksplit = 1;
        if (ksplit > 0) {
            float* P = (float*)d_ws;
            dim3 grid1((VOCAB + 63) / 64, ksplit);
            build_partial_folded<<<grid1, 256, 0, stream>>>(w1, b1, w2, P, HID / ksplit);
            gather_out<<<nblk2, 256, 0, stream>>>(idx, P, b2, out, ntok, ksplit);
        } else {
            int nblk = (ntok * 64 + 255) / 256;
            direct_kernel<<<nblk, 256, 0, stream>>>(idx, w1, b1, w2, b2, out, ntok);
        }
    }
}

// Round 13
// 51.057 us; speedup vs baseline: 1.6829x; 1.6829x over previous
//
#include <hip/hip_runtime.h>
#include <hip/hip_bf16.h>
#include <stdint.h>

#define VOCAB 50257
#define HID 512
#define LABELS 64
#define KSPLIT 4
#define KLEN 128           // HID / KSPLIT
#define TILEV 128
#define AP 36              // A row pitch in ushorts (32 h + 4 pad) = 72 B
#define BP 132             // B row pitch in ushorts (128 h + 4 pad) = 264 B

typedef __attribute__((ext_vector_type(8))) short bf16x8;
typedef __attribute__((ext_vector_type(4))) float f32x4;

__device__ __forceinline__ ushort f2bf(float x) {
    uint32_t u = __float_as_uint(x);
    return (ushort)((u + 0x7fffu + ((u >> 16) & 1u)) >> 16);   // RNE
}

__device__ __forceinline__ bf16x8 ld_frag(const ushort* p) {  // p 8B-aligned
    union { uint2 u[2]; bf16x8 v; } x;
    x.u[0] = *(const uint2*)(p);
    x.u[1] = *(const uint2*)(p + 4);
    return x.v;
}

// ---------------------------------------------------------------------------
// K0: C[l] = b2[l] + sum_h b1[h] * w2[l][h]  (bias kept exactly in fp32)
// ---------------------------------------------------------------------------
__global__ void bias_combine(const float* __restrict__ b1,
                             const float* __restrict__ w2,
                             const float* __restrict__ b2,
                             float* __restrict__ C)
{
    int l = threadIdx.x;   // 64 threads
    float s = b2[l];
    for (int h = 0; h < HID; h += 4) {
        float4 wv = *(const float4*)&w2[l * HID + h];
        float4 bv = *(const float4*)&b1[h];
        s += wv.x * bv.x + wv.y * bv.y + wv.z * bv.z + wv.w * bv.w;
    }
    C[l] = s;
}

// ---------------------------------------------------------------------------
// K1 (fast path): P[s][v][l] = sum_h w1[h,v]*w2[l,h] via bf16 MFMA 16x16x32.
// Block: 256 thr / 4 waves, tile 128v x 64l, K=KLEN in 4 chunks of 32.
// A staged TRANSPOSED [v][h] bf16 (pitch 72B -> b64 frag reads, <=2-way);
// B staged once [l][h] bf16. Wave wv owns v-rows [wv*32, +32): 2x4 frags.
// Single reg-set prefetch (R10-proven), 1 barrier per chunk, LDS dbuf for A.
// ---------------------------------------------------------------------------
#define LOAD_A(c)                                                             \
    {                                                                         \
        const float* g = &w1[(size_t)(hbase + (c)*32 + hh*16) * VOCAB + v0 + vc]; \
        if (fullA) {                                                          \
            _Pragma("unroll")                                                 \
            for (int i = 0; i < 16; ++i) r[i] = g[(size_t)i * VOCAB];         \
        } else {                                                              \
            bool ok = (v0 + vc) < VOCAB;                                      \
            _Pragma("unroll")                                                 \
            for (int i = 0; i < 16; ++i) r[i] = ok ? g[(size_t)i * VOCAB] : 0.f; \
        }                                                                     \
    }

#define WRITE_A(buf)                                                          \
    {                                                                         \
        ushort* base = &lA[buf][vc * AP + hh * 16];                           \
        _Pragma("unroll")                                                     \
        for (int i = 0; i < 16; i += 2) {                                     \
            uint32_t pk = (uint32_t)f2bf(r[i]) | ((uint32_t)f2bf(r[i + 1]) << 16); \
            *(uint32_t*)(base + i) = pk;                                      \
        }                                                                     \
    }

#define MFMA_B16(a, b, c) __builtin_amdgcn_mfma_f32_16x16x32_bf16(a, b, c, 0, 0, 0)

#define COMPUTE(buf, c)                                                       \
    {                                                                         \
        const ushort* ab = &lA[buf][(wv * 32 + lrow) * AP + kg * 8];          \
        bf16x8 a0 = ld_frag(ab);                                              \
        bf16x8 a1 = ld_frag(ab + 16 * AP);                                    \
        const ushort* bb = &lB[lrow * BP + (c) * 32 + kg * 8];                \
        bf16x8 b0 = ld_frag(bb);                                              \
        bf16x8 b1f = ld_frag(bb + 16 * BP);                                   \
        bf16x8 b2f = ld_frag(bb + 32 * BP);                                   \
        bf16x8 b3f = ld_frag(bb + 48 * BP);                                   \
        acc00 = MFMA_B16(a0, b0, acc00);  acc01 = MFMA_B16(a0, b1f, acc01);   \
        acc02 = MFMA_B16(a0, b2f, acc02); acc03 = MFMA_B16(a0, b3f, acc03);   \
        acc10 = MFMA_B16(a1, b0, acc10);  acc11 = MFMA_B16(a1, b1f, acc11);   \
        acc12 = MFMA_B16(a1, b2f, acc12); acc13 = MFMA_B16(a1, b3f, acc13);   \
    }

#define STORE_ONE(accv, m, n)                                                 \
    {                                                                         \
        int vb = v0 + wv * 32 + (m) * 16 + kg * 4;                            \
        int l  = (n) * 16 + lrow;                                             \
        _Pragma("unroll")                                                     \
        for (int rr = 0; rr < 4; ++rr)                                        \
            if (fullA || (vb + rr) < VOCAB)                                   \
                Pout[(size_t)(vb + rr) * LABELS + l] = accv[rr];              \
    }

__global__ __launch_bounds__(256) void build_mfma(
    const float* __restrict__ w1,   // [HID][VOCAB]
    const float* __restrict__ w2,   // [LABELS][HID]
    float* __restrict__ P)          // [KSPLIT][VOCAB][LABELS]
{
    __shared__ ushort lA[2][TILEV * AP];   // [v][h] bf16, transposed w1 chunk
    __shared__ ushort lB[LABELS * BP];     // [l][h] bf16, w2 K-slice

    const int t     = threadIdx.x;
    const int lane  = t & 63;
    const int wv    = t >> 6;       // wave 0..3 -> v-rows wv*32..+31
    const int lrow  = lane & 15;    // M-row (A) / N-col (B) / C col
    const int kg    = lane >> 4;    // k-group
    const int v0    = blockIdx.x * TILEV;
    const int hbase = blockIdx.y * KLEN;
    float* Pout = P + (size_t)blockIdx.y * VOCAB * LABELS;
    const bool fullA = (v0 + TILEV <= VOCAB);
    const int vc = t & 127;         // staging: this thread's v-column
    const int hh = t >> 7;          // staging: h-half (0/1)

    f32x4 acc00 = {0,0,0,0}, acc01 = {0,0,0,0}, acc02 = {0,0,0,0}, acc03 = {0,0,0,0};
    f32x4 acc10 = {0,0,0,0}, acc11 = {0,0,0,0}, acc12 = {0,0,0,0}, acc13 = {0,0,0,0};
    float r[16];

    // ---- prologue: A chunk0 -> regs; B (all KLEN) -> LDS; A regs -> LDS buf0
    LOAD_A(0);
    {   // stage w2 slice: thread owns h-col (t&127), l = hh + 2i
        _Pragma("unroll")
        for (int i = 0; i < 32; ++i) {
            int l = hh + 2 * i;
            lB[l * BP + vc] = f2bf(w2[l * HID + hbase + vc]);
        }
    }
    WRITE_A(0);
    __syncthreads();

    // ---- 4 chunks, LDS double-buffered, 1 barrier per chunk
    LOAD_A(1); COMPUTE(0, 0); WRITE_A(1); __syncthreads();
    LOAD_A(2); COMPUTE(1, 1); WRITE_A(0); __syncthreads();
    LOAD_A(3); COMPUTE(0, 2); WRITE_A(1); __syncthreads();
    COMPUTE(1, 3);

    STORE_ONE(acc00, 0, 0); STORE_ONE(acc01, 0, 1);
    STORE_ONE(acc02, 0, 2); STORE_ONE(acc03, 0, 3);
    STORE_ONE(acc10, 1, 0); STORE_ONE(acc11, 1, 1);
    STORE_ONE(acc12, 1, 2); STORE_ONE(acc13, 1, 3);
}

// ---------------------------------------------------------------------------
// K1 fallback (small ws): folded-b1 fp32 single-buffer version (R7, proven).
// ---------------------------------------------------------------------------
__global__ __launch_bounds__(256) void build_partial_folded(
    const float* __restrict__ w1,
    const float* __restrict__ b1,
    const float* __restrict__ w2,
    float* __restrict__ P,
    int klen)
{
    __shared__ float lds_a[32 * 68];
    __shared__ float lds_b[32 * 68];

    const int t     = threadIdx.x;
    const int v0    = blockIdx.x * 64;
    const int hbase = blockIdx.y * klen;
    float* Pout = P + (size_t)blockIdx.y * VOCAB * LABELS;
    const int tx = t & 15;
    const int ty = t >> 4;
    const bool full = (v0 + 64 <= VOCAB);

    float acc[4][4] = {};

    for (int h0 = hbase; h0 < hbase + klen; h0 += 32) {
#pragma unroll
        for (int i = 0; i < 8; ++i) {
            int e   = t + 256 * i;
            int row = e >> 6;
            int col = e & 63;
            int v   = v0 + col;
            float a = (full || v < VOCAB) ? w1[(size_t)(h0 + row) * VOCAB + v] : 0.f;
            lds_a[row * 68 + col] = a + b1[h0 + row];
        }
#pragma unroll
        for (int i = 0; i < 2; ++i) {
            int e   = t + 256 * i;
            int hh4 = e >> 6;
            int l   = e & 63;
            float4 bv = *(const float4*)&w2[l * HID + h0 + hh4 * 4];
            lds_b[(hh4 * 4 + 0) * 68 + l] = bv.x;
            lds_b[(hh4 * 4 + 1) * 68 + l] = bv.y;
            lds_b[(hh4 * 4 + 2) * 68 + l] = bv.z;
            lds_b[(hh4 * 4 + 3) * 68 + l] = bv.w;
        }
        __syncthreads();
#pragma unroll
        for (int hh2 = 0; hh2 < 32; ++hh2) {
            float4 a = *(const float4*)&lds_a[hh2 * 68 + tx * 4];
            float4 b = *(const float4*)&lds_b[hh2 * 68 + ty * 4];
            acc[0][0] += a.x * b.x; acc[0][1] += a.x * b.y; acc[0][2] += a.x * b.z; acc[0][3] += a.x * b.w;
            acc[1][0] += a.y * b.x; acc[1][1] += a.y * b.y; acc[1][2] += a.y * b.z; acc[1][3] += a.y * b.w;
            acc[2][0] += a.z * b.x; acc[2][1] += a.z * b.y; acc[2][2] += a.z * b.z; acc[2][3] += a.z * b.w;
            acc[3][0] += a.w * b.x; acc[3][1] += a.w * b.y; acc[3][2] += a.w * b.z; acc[3][3] += a.w * b.w;
        }
        __syncthreads();
    }

#pragma unroll
    for (int i = 0; i < 4; ++i) {
        int v = v0 + tx * 4 + i;
        if (v < VOCAB) {
            *(float4*)&Pout[(size_t)v * LABELS + ty * 4] =
                make_float4(acc[i][0], acc[i][1], acc[i][2], acc[i][3]);
        }
    }
}

// ---------------------------------------------------------------------------
// K2: out[tok][l] = sum_s P[s][idx[tok]][l] + bias[l]
// ---------------------------------------------------------------------------
__global__ __launch_bounds__(256) void gather_out(
    const int* __restrict__ idx,
    const float* __restrict__ P,
    const float* __restrict__ bias,
    float* __restrict__ out,
    int ntok, int ksplit)
{
    int g   = blockIdx.x * 256 + threadIdx.x;
    int tok = g >> 4;
    int j   = g & 15;
    if (tok >= ntok) return;
    int v = idx[tok];
    float4 s = ((const float4*)bias)[j];
    const float4* p = (const float4*)P + (size_t)v * 16 + j;
    for (int k = 0; k < ksplit; ++k) {
        float4 m = p[(size_t)k * VOCAB * 16];
        s.x += m.x; s.y += m.y; s.z += m.z; s.w += m.w;
    }
    ((float4*)out)[(size_t)tok * 16 + j] = s;
}

// ---------------------------------------------------------------------------
// Fallback (ws too small for any table): direct per-token dot.
// ---------------------------------------------------------------------------
__global__ __launch_bounds__(256) void direct_kernel(
    const int* __restrict__ idx,
    const float* __restrict__ w1,
    const float* __restrict__ b1,
    const float* __restrict__ w2,
    const float* __restrict__ b2,
    float* __restrict__ out,
    int ntok)
{
    int g   = blockIdx.x * 256 + threadIdx.x;
    int tok = g >> 6;
    int l   = g & 63;
    if (tok >= ntok) return;
    int v = idx[tok];
    float acc = b2[l];
    for (int h = 0; h < HID; ++h)
        acc += (w1[(size_t)h * VOCAB + v] + b1[h]) * w2[l * HID + h];
    out[(size_t)tok * 64 + l] = acc;
}

extern "C" void kernel_launch(void* const* d_in, const int* in_sizes, int n_in,
                              void* d_out, int out_size, void* d_ws, size_t ws_size,
                              hipStream_t stream) {
    const int*   idx = (const int*)d_in[0];
    const float* w1  = (const float*)d_in[1];
    const float* b1  = (const float*)d_in[2];
    const float* w2  = (const float*)d_in[3];
    const float* b2  = (const float*)d_in[4];
    float* out = (float*)d_out;
    const int ntok = in_sizes[0];   // 8*4096 = 32768

    const size_t table_bytes = (size_t)VOCAB * LABELS * sizeof(float);  // ~12.9 MB
    const int nblk2 = (ntok * 16 + 255) / 256;                          // 2048

    if (ws_size >= (size_t)KSPLIT * table_bytes + 1024) {
        // fast path: MFMA build (pure product) + exact fp32 bias in ws tail
        float* P = (float*)d_ws;
        float* C = (float*)((char*)d_ws + (size_t)KSPLIT * table_bytes);
        bias_combine<<<1, 64, 0, stream>>>(b1, w2, b2, C);
        dim3 grid1((VOCAB + TILEV - 1) / TILEV, KSPLIT);   // 393 x 4 = 1572
        build_mfma<<<grid1, 256, 0, stream>>>(w1, w2, P);
        gather_out<<<nblk2, 256, 0, stream>>>(idx, P, C, out, ntok, KSPLIT);
    } else {
        int ksplit = 0;
        if      (ws_size >= 4 * table_bytes) ksplit = 4;
        else if (ws_size >= 2 * table_bytes) ksplit = 2;
        else if (ws_size >= 1 * table_bytes) ksplit = 1;
        if (ksplit > 0) {
            float* P = (float*)d_ws;
            dim3 grid1((VOCAB + 63) / 64, ksplit);
            build_partial_folded<<<grid1, 256, 0, stream>>>(w1, b1, w2, P, HID / ksplit);
            gather_out<<<nblk2, 256, 0, stream>>>(idx, P, b2, out, ntok, ksplit);
        } else {
            int nblk = (ntok * 64 + 255) / 256;
            direct_kernel<<<nblk, 256, 0, stream>>>(idx, w1, b1, w2, b2, out, ntok);
        }
    }
}